// Round 5
// baseline (1928.108 us; speedup 1.0000x reference)
//
#include <hip/hip_runtime.h>

// Problem constants (fixed by reference setup_inputs)
#define NB    16              // batch
#define CIN_  64              // input channels of x
#define COUT_ 128             // channels of z / output
#define PLANE_ 1024           // 32*32
#define DDIM  (COUT_*PLANE_)  // 131072
#define BDTOT ((size_t)NB*DDIM) // 2097152
#define KMAX  20              // Broyden threshold

typedef short  bfrag __attribute__((ext_vector_type(8)));  // 8 bf16 (4 VGPRs)
typedef float  ffrag __attribute__((ext_vector_type(4)));  // 4 fp32 acc

// bf16 <-> fp32 helpers (RNE)
__device__ __forceinline__ float bf2f(unsigned short h) {
    return __uint_as_float(((unsigned int)h) << 16);
}
__device__ __forceinline__ unsigned short f2bf(float f) {
    unsigned int u = __float_as_uint(f);
    u = (u + 0x7FFFu + ((u >> 16) & 1u)) >> 16;
    return (unsigned short)u;
}
__device__ __forceinline__ void bf2x(unsigned int w, float& lo, float& hi) {
    lo = __uint_as_float(w << 16);
    hi = __uint_as_float(w & 0xffff0000u);
}
__device__ __forceinline__ unsigned int packbf(float lo, float hi) {
    return ((unsigned int)f2bf(hi) << 16) | (unsigned int)f2bf(lo);
}
__device__ __forceinline__ void ub4(ushort4 a, float* f) {
    f[0] = bf2f(a.x); f[1] = bf2f(a.y); f[2] = bf2f(a.z); f[3] = bf2f(a.w);
}
__device__ __forceinline__ ushort4 pk4(const float* f) {
    ushort4 r; r.x = f2bf(f[0]); r.y = f2bf(f[1]); r.z = f2bf(f[2]); r.w = f2bf(f[3]);
    return r;
}
__device__ __forceinline__ float wred(float v) {
    #pragma unroll
    for (int m = 32; m > 0; m >>= 1) v += __shfl_xor(v, m, 64);
    return v;
}

// ---------------------------------------------------------------------------
// Shared MFMA conv core: one wave = 32co x 32px tile, NHWC bf16 input.
// ---------------------------------------------------------------------------
template<int CIN>
__device__ __forceinline__ void conv_core(
    const unsigned short* __restrict__ zb, const unsigned short* __restrict__ Wt,
    int hrow, int co_base, int n, int col, int quad, ffrag accs[4])
{
    const bfrag bzero = {0,0,0,0,0,0,0,0};
    const int w0 = col, w1 = col + 16;
    const size_t zbase = (size_t)n * PLANE_ * CIN;
    #pragma unroll
    for (int tap = 0; tap < 9; ++tap) {
        const int dh = tap / 3 - 1, dw = tap % 3 - 1;
        const int sh = hrow + dh;
        const bool rowok = (unsigned)sh < 32u;
        const int sw0 = w0 + dw, sw1 = w1 + dw;
        const bool v0 = rowok && (unsigned)sw0 < 32u;
        const bool v1 = rowok && (unsigned)sw1 < 32u;
        const int sp0 = v0 ? (sh * 32 + sw0) : (hrow * 32 + w0);
        const int sp1 = v1 ? (sh * 32 + sw1) : (hrow * 32 + w1);
        const unsigned short* z0 = zb + zbase + (size_t)sp0 * CIN + quad * 8;
        const unsigned short* z1 = zb + zbase + (size_t)sp1 * CIN + quad * 8;
        const unsigned short* wr0 = Wt + ((size_t)tap * COUT_ + co_base + col) * CIN + quad * 8;
        const unsigned short* wr1 = wr0 + 16 * CIN;
        #pragma unroll
        for (int cb = 0; cb < CIN; cb += 32) {
            bfrag a0 = *(const bfrag*)(wr0 + cb);
            bfrag a1 = *(const bfrag*)(wr1 + cb);
            bfrag b0 = *(const bfrag*)(z0 + cb);
            bfrag b1 = *(const bfrag*)(z1 + cb);
            if (!v0) b0 = bzero;
            if (!v1) b1 = bzero;
            accs[0] = __builtin_amdgcn_mfma_f32_16x16x32_bf16(a0, b0, accs[0], 0, 0, 0);
            accs[1] = __builtin_amdgcn_mfma_f32_16x16x32_bf16(a0, b1, accs[1], 0, 0, 0);
            accs[2] = __builtin_amdgcn_mfma_f32_16x16x32_bf16(a1, b0, accs[2], 0, 0, 0);
            accs[3] = __builtin_amdgcn_mfma_f32_16x16x32_bf16(a1, b1, accs[3], 0, 0, 0);
        }
    }
}

// ---------------------------------------------------------------------------
// ux = conv(x,U) + b : writes fp32 ux (for final recompute) + bf16 uxb (loop).
// ---------------------------------------------------------------------------
__global__ __launch_bounds__(64) void conv_ux_kernel(
    const unsigned short* __restrict__ xinb, const unsigned short* __restrict__ WU,
    const float* __restrict__ bias, float* __restrict__ ux,
    unsigned short* __restrict__ uxb)
{
    const int hrow = blockIdx.x, coT = blockIdx.y, n = blockIdx.z;
    const int lane = threadIdx.x, col = lane & 15, quad = lane >> 4;
    ffrag accs[4] = {{0.f,0.f,0.f,0.f},{0.f,0.f,0.f,0.f},{0.f,0.f,0.f,0.f},{0.f,0.f,0.f,0.f}};
    conv_core<CIN_>(xinb, WU, hrow, coT * 32, n, col, quad, accs);
    #pragma unroll
    for (int f = 0; f < 4; ++f) {
        const int mt = f >> 1, nt = f & 1;
        const int co = coT * 32 + mt * 16 + quad * 4;
        const int px = hrow * 32 + nt * 16 + col;
        const size_t o = ((size_t)n * PLANE_ + px) * COUT_ + co;
        float4 bv = *(const float4*)(bias + co);
        float r[4] = {accs[f][0] + bv.x, accs[f][1] + bv.y, accs[f][2] + bv.z, accs[f][3] + bv.w};
        *(float4*)(ux + o) = make_float4(r[0], r[1], r[2], r[3]);
        *(ushort4*)(uxb + o) = pk4(r);
    }
}

// ---------------------------------------------------------------------------
// Fused Broyden conv: g = relu(conv(z,A)+ux) - x ; dgx = g - gx_old (in place)
// plus ALL reduction dots for this iteration:
//   rows [0,K): t_i = v_i.g   rows [K,2K): q_i = v_i.dgx
//   rows [2K,3K): p_i = u_i.dx   row 3K: dx.dgx  3K+1: dx.g  3K+2: g.g
// cparts[(row*NB+n)*128 + blk],  blk = hrow*4+coT.
// ---------------------------------------------------------------------------
__global__ __launch_bounds__(64) void conv_bro_kernel(
    const unsigned short* __restrict__ zb, const unsigned short* __restrict__ WA,
    const unsigned short* __restrict__ uxb, const float* __restrict__ xv,
    unsigned short* gxb,                       // rw (old -> new)
    const unsigned short* __restrict__ updb,   // dx
    unsigned short* __restrict__ dgxb,
    const unsigned short* __restrict__ Us, const unsigned short* __restrict__ VTs,
    float* __restrict__ cparts, int kd)
{
    const int hrow = blockIdx.x, coT = blockIdx.y, n = blockIdx.z;
    const int lane = threadIdx.x, col = lane & 15, quad = lane >> 4;
    ffrag accs[4] = {{0.f,0.f,0.f,0.f},{0.f,0.f,0.f,0.f},{0.f,0.f,0.f,0.f},{0.f,0.f,0.f,0.f}};
    conv_core<COUT_>(zb, WA, hrow, coT * 32, n, col, quad, accs);

    const int blk = hrow * 4 + coT;
    float g[16], dgv[16], up[16];
    size_t off[4];
    #pragma unroll
    for (int f = 0; f < 4; ++f) {
        const int mt = f >> 1, nt = f & 1;
        const int co = coT * 32 + mt * 16 + quad * 4;
        const int px = hrow * 32 + nt * 16 + col;
        const size_t o = ((size_t)n * PLANE_ + px) * COUT_ + co;
        off[f] = o;
        float uxv[4], gov[4], udv[4];
        ub4(*(const ushort4*)(uxb + o), uxv);
        ub4(*(const ushort4*)(gxb + o), gov);
        ub4(*(const ushort4*)(updb + o), udv);
        float4 xc = *(const float4*)(xv + o);
        #pragma unroll
        for (int r = 0; r < 4; ++r) {
            float tv = accs[f][r] + uxv[r];
            tv = tv > 0.f ? tv : 0.f;
            float gg = tv - (&xc.x)[r];
            g[f*4+r] = gg;
            dgv[f*4+r] = gg - gov[r];
            up[f*4+r] = udv[r];
        }
        *(ushort4*)(gxb + o)  = pk4(&g[f*4]);
        *(ushort4*)(dgxb + o) = pk4(&dgv[f*4]);
    }

    float sdd = 0.f, sdg = 0.f, sob = 0.f;
    #pragma unroll
    for (int j = 0; j < 16; ++j) {
        sdd += up[j] * dgv[j];
        sdg += up[j] * g[j];
        sob += g[j] * g[j];
    }
    for (int i = 0; i < kd; ++i) {
        const unsigned short* Ub = Us  + (size_t)i * BDTOT;
        const unsigned short* Vb = VTs + (size_t)i * BDTOT;
        float tp = 0.f, qp = 0.f, pp = 0.f;
        #pragma unroll
        for (int f = 0; f < 4; ++f) {
            float fv[4], fu[4];
            ub4(*(const ushort4*)(Vb + off[f]), fv);
            ub4(*(const ushort4*)(Ub + off[f]), fu);
            #pragma unroll
            for (int r = 0; r < 4; ++r) {
                tp += fv[r] * g[f*4+r];
                qp += fv[r] * dgv[f*4+r];
                pp += fu[r] * up[f*4+r];
            }
        }
        tp = wred(tp); qp = wred(qp); pp = wred(pp);
        if (lane == 0) {
            cparts[((size_t)i * NB + n) * 128 + blk] = tp;
            cparts[((size_t)(KMAX + i) * NB + n) * 128 + blk] = qp;
            cparts[((size_t)(2 * KMAX + i) * NB + n) * 128 + blk] = pp;
        }
    }
    sdd = wred(sdd); sdg = wred(sdg); sob = wred(sob);
    if (lane == 0) {
        cparts[((size_t)(3 * KMAX)     * NB + n) * 128 + blk] = sdd;
        cparts[((size_t)(3 * KMAX + 1) * NB + n) * 128 + blk] = sdg;
        cparts[((size_t)(3 * KMAX + 2) * NB + n) * 128 + blk] = sob;
    }
}

// ---------------------------------------------------------------------------
// Final recompute: out = relu(conv(best,A) + ux_fp32)  -> NCHW
// ---------------------------------------------------------------------------
__global__ __launch_bounds__(64) void conv_final_kernel(
    const unsigned short* __restrict__ bestzb, const unsigned short* __restrict__ WA,
    const float* __restrict__ ux, float* __restrict__ out)
{
    const int hrow = blockIdx.x, coT = blockIdx.y, n = blockIdx.z;
    const int lane = threadIdx.x, col = lane & 15, quad = lane >> 4;
    ffrag accs[4] = {{0.f,0.f,0.f,0.f},{0.f,0.f,0.f,0.f},{0.f,0.f,0.f,0.f},{0.f,0.f,0.f,0.f}};
    conv_core<COUT_>(bestzb, WA, hrow, coT * 32, n, col, quad, accs);
    #pragma unroll
    for (int f = 0; f < 4; ++f) {
        const int mt = f >> 1, nt = f & 1;
        const int co = coT * 32 + mt * 16 + quad * 4;
        const int px = hrow * 32 + nt * 16 + col;
        const size_t o = ((size_t)n * PLANE_ + px) * COUT_ + co;
        float4 uv = *(const float4*)(ux + o);
        #pragma unroll
        for (int r = 0; r < 4; ++r) {
            float t = accs[f][r] + (&uv.x)[r];
            out[((size_t)n * COUT_ + co + r) * PLANE_ + px] = t > 0.f ? t : 0.f;
        }
    }
}

// ---------------------------------------------------------------------------
// One-time prep
// ---------------------------------------------------------------------------
#define NWA (9 * 128 * 128)
#define NWU (9 * 128 * 64)
__global__ __launch_bounds__(256) void prep_w_kernel(
    const float* __restrict__ A, const float* __restrict__ U,
    unsigned short* __restrict__ WA, unsigned short* __restrict__ WU)
{
    int idx = blockIdx.x * 256 + threadIdx.x;
    if (idx < NWA) {
        int tap = idx / (128 * 128), r = idx % (128 * 128);
        int co = r >> 7, ci = r & 127;
        WA[idx] = f2bf(A[(co * 128 + ci) * 9 + tap]);
    } else if (idx < NWA + NWU) {
        int j = idx - NWA;
        int tap = j / (128 * 64), r = j % (128 * 64);
        int co = r >> 6, ci = r & 63;
        WU[j] = f2bf(U[(co * 64 + ci) * 9 + tap]);
    }
}

__global__ __launch_bounds__(256) void prep_xin_kernel(
    const float* __restrict__ x, unsigned short* __restrict__ xb)
{
    int idx = blockIdx.x * 256 + threadIdx.x;   // over 16*1024*64
    int n = idx >> 16, r = idx & 65535;
    int px = r >> 6, ci = r & 63;
    xb[idx] = f2bf(x[(n * 64 + ci) * 1024 + px]);
}

__global__ __launch_bounds__(256) void fill0_kernel(float* __restrict__ a)
{
    size_t i = ((size_t)blockIdx.x * 256 + threadIdx.x) * 4;
    *(float4*)(a + i) = make_float4(0.f, 0.f, 0.f, 0.f);
}

// ---------------------------------------------------------------------------
// Init: gx0 = upd0 = relu(ux) (bf16-rounded), x1 = rounded value (fp32 store),
// zb = bf16(x1); per-block obj partial -> objinit[1024].
// ---------------------------------------------------------------------------
__global__ __launch_bounds__(256) void ew_init_kernel(
    const float* __restrict__ ux, unsigned short* __restrict__ gxb,
    unsigned short* __restrict__ updb, float* __restrict__ xv,
    unsigned short* __restrict__ zb, float* __restrict__ objinit)
{
    const int tid = threadIdx.x;
    size_t i = ((size_t)blockIdx.x * 256 + tid) * 8;
    float rr[8];
    float ob = 0.f;
    #pragma unroll
    for (int h = 0; h < 2; ++h) {
        float4 u = *(const float4*)(ux + i + h * 4);
        #pragma unroll
        for (int r = 0; r < 4; ++r) {
            float v = (&u.x)[r];
            v = v > 0.f ? v : 0.f;
            v = bf2f(f2bf(v));           // round to bf16 once, use consistently
            rr[h*4+r] = v;
            ob += v * v;
        }
    }
    uint4 m = {packbf(rr[0],rr[1]), packbf(rr[2],rr[3]), packbf(rr[4],rr[5]), packbf(rr[6],rr[7])};
    *(uint4*)(gxb  + i) = m;
    *(uint4*)(updb + i) = m;
    *(uint4*)(zb   + i) = m;
    #pragma unroll
    for (int h = 0; h < 2; ++h)
        *(float4*)(xv + i + h * 4) = make_float4(rr[h*4+0], rr[h*4+1], rr[h*4+2], rr[h*4+3]);

    __shared__ float so[256];
    so[tid] = ob;
    __syncthreads();
    for (int s = 128; s > 0; s >>= 1) {
        if (tid < s) so[tid] += so[tid + s];
        __syncthreads();
    }
    if (tid == 0) objinit[blockIdx.x] = so[0];
}

// ---------------------------------------------------------------------------
// Fold partials; scalar math; best tracking.
// phase 0: best2 = sum objinit. phase 1: full. phase 2: obj only.
// ---------------------------------------------------------------------------
__global__ __launch_bounds__(256) void small_kernel(
    const float* __restrict__ cparts, const float* __restrict__ objinit,
    float* __restrict__ p, float* __restrict__ q, float* __restrict__ t,
    float* __restrict__ denom, float* __restrict__ c,
    float* __restrict__ best2, float* __restrict__ flag,
    int k, int phase)
{
    const int tid = threadIdx.x;
    if (phase == 1 && k > 0) {
        for (int idx = tid; idx < NB * k; idx += 256) {
            int b = idx / k, i = idx - b * k;
            const float* T = cparts + ((size_t)i * NB + b) * 128;
            const float* Q = cparts + ((size_t)(KMAX + i) * NB + b) * 128;
            const float* P = cparts + ((size_t)(2 * KMAX + i) * NB + b) * 128;
            float tv = 0.f, qv = 0.f, pv = 0.f;
            for (int j = 0; j < 128; ++j) { tv += T[j]; qv += Q[j]; pv += P[j]; }
            t[b * KMAX + i] = tv; q[b * KMAX + i] = qv; p[b * KMAX + i] = pv;
        }
    }
    __syncthreads();
    if (phase == 1 && tid < NB) {
        int b = tid;
        const float* DD = cparts + ((size_t)(3 * KMAX) * NB + b) * 128;
        const float* DG = cparts + ((size_t)(3 * KMAX + 1) * NB + b) * 128;
        float ddv = 0.f, dgv = 0.f;
        for (int j = 0; j < 128; ++j) { ddv += DD[j]; dgv += DG[j]; }
        float pq = 0.f, pt = 0.f;
        for (int i = 0; i < k; ++i) {
            pq += p[b * KMAX + i] * q[b * KMAX + i];
            pt += p[b * KMAX + i] * t[b * KMAX + i];
        }
        float den = -ddv + pq;
        if (fabsf(den) < 1e-9f) den = 1e-9f;
        denom[b] = den;
        c[b] = (-dgv + pt) / den;
    }
    // objective (all phases)
    float o = 0.f;
    if (phase == 0) {
        for (int j = tid; j < 1024; j += 256) o += objinit[j];
    } else {
        const float* OB = cparts + (size_t)(3 * KMAX + 2) * NB * 128;
        for (int j = tid; j < NB * 128; j += 256) o += OB[j];
    }
    __shared__ float so[256];
    so[tid] = o;
    __syncthreads();
    for (int s = 128; s > 0; s >>= 1) {
        if (tid < s) so[tid] += so[tid + s];
        __syncthreads();
    }
    if (tid == 0) {
        float ot = so[0];
        if (phase == 0) { *best2 = ot; *flag = 0.f; }
        else {
            float bo = *best2;
            *flag = (ot < bo) ? 1.f : 0.f;
            if (ot < bo) *best2 = ot;
        }
    }
}

// ---------------------------------------------------------------------------
// Fused big pass: history read once; writes new rows; advances x; mirrors.
// v_k = -dx + sum p_i v_i
// u_k = (dx + dgx - sum q_i u_i) / denom
// upd_new = gx - c*(dx+dgx) - sum t_i u_i + c*sum q_i u_i   (bf16-rounded)
// if flag: bestzb = bf16(x_cur);  x_next = x_cur + upd_new_rounded
// grid = (DDIM/2048, NB), 8 elems/thread.
// ---------------------------------------------------------------------------
__global__ __launch_bounds__(256) void pass2_kernel(
    unsigned short* __restrict__ Us, unsigned short* __restrict__ VTs,
    unsigned short* updb,                 // rw: dx in, new update out
    const unsigned short* __restrict__ dgxb, const unsigned short* __restrict__ gxb,
    float* xv, unsigned short* __restrict__ zb, unsigned short* __restrict__ bestzb,
    const float* __restrict__ p, const float* __restrict__ q, const float* __restrict__ t,
    const float* __restrict__ denom, const float* __restrict__ c,
    const float* __restrict__ flag, int k)
{
    const int b = blockIdx.y;
    const int tid = threadIdx.x;
    __shared__ float sp[KMAX], sq[KMAX], st[KMAX];
    __shared__ float sden, sc, sflag;
    if (tid < k) {
        sp[tid] = p[b * KMAX + tid];
        sq[tid] = q[b * KMAX + tid];
        st[tid] = t[b * KMAX + tid];
    }
    if (tid == 0) { sden = denom[b]; sc = c[b]; sflag = flag[0]; }
    __syncthreads();

    const size_t base = (size_t)b * DDIM + ((size_t)blockIdx.x * 256 + tid) * 8;
    float xd[8], dg[8], gv[8];
    {
        uint4 a = *(const uint4*)(updb + base);
        uint4 d = *(const uint4*)(dgxb + base);
        uint4 g = *(const uint4*)(gxb + base);
        bf2x(a.x, xd[0], xd[1]); bf2x(a.y, xd[2], xd[3]);
        bf2x(a.z, xd[4], xd[5]); bf2x(a.w, xd[6], xd[7]);
        bf2x(d.x, dg[0], dg[1]); bf2x(d.y, dg[2], dg[3]);
        bf2x(d.z, dg[4], dg[5]); bf2x(d.w, dg[6], dg[7]);
        bf2x(g.x, gv[0], gv[1]); bf2x(g.y, gv[2], gv[3]);
        bf2x(g.z, gv[4], gv[5]); bf2x(g.w, gv[6], gv[7]);
    }
    float S1[8], S2[8], SV[8];
    #pragma unroll
    for (int j = 0; j < 8; ++j) { S1[j] = 0.f; S2[j] = 0.f; SV[j] = 0.f; }

    for (int i = 0; i < k; ++i) {
        uint4 uu = *(const uint4*)(Us  + (size_t)i * BDTOT + base);
        uint4 vv = *(const uint4*)(VTs + (size_t)i * BDTOT + base);
        float uvals[8], vvals[8];
        bf2x(uu.x, uvals[0], uvals[1]); bf2x(uu.y, uvals[2], uvals[3]);
        bf2x(uu.z, uvals[4], uvals[5]); bf2x(uu.w, uvals[6], uvals[7]);
        bf2x(vv.x, vvals[0], vvals[1]); bf2x(vv.y, vvals[2], vvals[3]);
        bf2x(vv.z, vvals[4], vvals[5]); bf2x(vv.w, vvals[6], vvals[7]);
        float qi = sq[i], ti = st[i], pi = sp[i];
        #pragma unroll
        for (int j = 0; j < 8; ++j) {
            S1[j] = fmaf(qi, uvals[j], S1[j]);
            S2[j] = fmaf(ti, uvals[j], S2[j]);
            SV[j] = fmaf(pi, vvals[j], SV[j]);
        }
    }

    float vk[8], uk[8], up[8];
    #pragma unroll
    for (int j = 0; j < 8; ++j) {
        vk[j] = -xd[j] + SV[j];
        uk[j] = (xd[j] + dg[j] - S1[j]) / sden;
        up[j] = gv[j] - sc * (xd[j] + dg[j]) - S2[j] + sc * S1[j];
    }
    uint4 vks = {packbf(vk[0],vk[1]), packbf(vk[2],vk[3]), packbf(vk[4],vk[5]), packbf(vk[6],vk[7])};
    uint4 uks = {packbf(uk[0],uk[1]), packbf(uk[2],uk[3]), packbf(uk[4],uk[5]), packbf(uk[6],uk[7])};
    *(uint4*)(VTs + (size_t)k * BDTOT + base) = vks;
    *(uint4*)(Us  + (size_t)k * BDTOT + base) = uks;

    uint4 upw = {packbf(up[0],up[1]), packbf(up[2],up[3]), packbf(up[4],up[5]), packbf(up[6],up[7])};
    *(uint4*)(updb + base) = upw;
    float upr[8];
    bf2x(upw.x, upr[0], upr[1]); bf2x(upw.y, upr[2], upr[3]);
    bf2x(upw.z, upr[4], upr[5]); bf2x(upw.w, upr[6], upr[7]);

    float xc[8];
    #pragma unroll
    for (int h = 0; h < 2; ++h) {
        float4 a = *(const float4*)(xv + base + h * 4);
        xc[h*4+0]=a.x; xc[h*4+1]=a.y; xc[h*4+2]=a.z; xc[h*4+3]=a.w;
    }
    if (sflag != 0.f) {
        uint4 bz = {packbf(xc[0],xc[1]), packbf(xc[2],xc[3]),
                    packbf(xc[4],xc[5]), packbf(xc[6],xc[7])};
        *(uint4*)(bestzb + base) = bz;
    }
    float xn[8];
    #pragma unroll
    for (int j = 0; j < 8; ++j) xn[j] = xc[j] + upr[j];
    #pragma unroll
    for (int h = 0; h < 2; ++h)
        *(float4*)(xv + base + h * 4) = make_float4(xn[h*4+0], xn[h*4+1], xn[h*4+2], xn[h*4+3]);
    uint4 zn = {packbf(xn[0],xn[1]), packbf(xn[2],xn[3]), packbf(xn[4],xn[5]), packbf(xn[6],xn[7])};
    *(uint4*)(zb + base) = zn;
}

// best mirror = zb when new best (last iteration only)
__global__ __launch_bounds__(256) void bestcopy_kernel(
    const float* __restrict__ flag, const unsigned short* __restrict__ zb,
    unsigned short* __restrict__ bestzb)
{
    if (flag[0] == 0.f) return;
    size_t i = ((size_t)blockIdx.x * 256 + threadIdx.x) * 8;
    *(uint4*)(bestzb + i) = *(const uint4*)(zb + i);
}

// ---------------------------------------------------------------------------
extern "C" void kernel_launch(void* const* d_in, const int* in_sizes, int n_in,
                              void* d_out, int out_size, void* d_ws, size_t ws_size,
                              hipStream_t stream)
{
    (void)in_sizes; (void)n_in; (void)out_size; (void)ws_size;
    const float* x  = (const float*)d_in[0];   // [16,64,32,32]
    const float* A  = (const float*)d_in[1];   // [128,128,3,3]
    const float* U  = (const float*)d_in[2];   // [128,64,3,3]
    const float* bb = (const float*)d_in[3];   // [128]
    float* out = (float*)d_out;

    char* w = (char*)d_ws;
    size_t off = 0;
    auto alloc = [&](size_t bytes) -> void* {
        void* pp = (void*)(w + off);
        off += (bytes + 255) & ~(size_t)255;
        return pp;
    };
    const size_t BDB  = BDTOT * sizeof(float);  // 8 MB
    const size_t BDH  = BDTOT * 2;              // 4 MB (bf16)
    float* ux    = (float*)alloc(BDB);          // fp32 (final recompute)
    float* xv    = (float*)alloc(BDB);          // fp32 iterate accumulator
    unsigned short* uxb    = (unsigned short*)alloc(BDH);
    unsigned short* gxb    = (unsigned short*)alloc(BDH);
    unsigned short* updb   = (unsigned short*)alloc(BDH);
    unsigned short* dgxb   = (unsigned short*)alloc(BDH);
    unsigned short* zb     = (unsigned short*)alloc(BDH);
    unsigned short* bestzb = (unsigned short*)alloc(BDH);
    unsigned short* xinb   = (unsigned short*)alloc((size_t)NB * PLANE_ * CIN_ * 2);
    unsigned short* WA     = (unsigned short*)alloc((size_t)NWA * 2);
    unsigned short* WU     = (unsigned short*)alloc((size_t)NWU * 2);
    unsigned short* Us  = (unsigned short*)alloc((size_t)KMAX * BDTOT * 2); // 84 MB
    unsigned short* VTs = (unsigned short*)alloc((size_t)KMAX * BDTOT * 2); // 84 MB
    float* cparts = (float*)alloc((size_t)(3 * KMAX + 3) * NB * 128 * sizeof(float));
    float* objinit= (float*)alloc(1024 * sizeof(float));
    float* p     = (float*)alloc(NB * KMAX * sizeof(float));
    float* q     = (float*)alloc(NB * KMAX * sizeof(float));
    float* t     = (float*)alloc(NB * KMAX * sizeof(float));
    float* denom = (float*)alloc(NB * sizeof(float));
    float* c     = (float*)alloc(NB * sizeof(float));
    float* best2 = (float*)alloc(sizeof(float));
    float* flag  = (float*)alloc(sizeof(float));

    const dim3 CG(32, 4, NB);                   // conv grid, 64-thr blocks
    const int I8WG = (int)(BDTOT / (256 * 8));  // 1024 blocks, 8 elems/thread

    // -------- one-time prep --------
    prep_w_kernel<<<(NWA + NWU + 255) / 256, 256, 0, stream>>>(A, U, WA, WU);
    prep_xin_kernel<<<(NB * PLANE_ * CIN_) / 256, 256, 0, stream>>>(x, xinb);
    fill0_kernel<<<(int)(BDH / (256 * 16)), 256, 0, stream>>>((float*)bestzb); // best = x0 = 0

    // ux = conv(x,U)+b (fp32 + bf16)
    conv_ux_kernel<<<CG, 64, 0, stream>>>(xinb, WU, bb, ux, uxb);
    // gx0 = upd0 = relu(ux); x1 = same; zb mirror; obj partials
    ew_init_kernel<<<I8WG, 256, 0, stream>>>(ux, gxb, updb, xv, zb, objinit);
    small_kernel<<<1, 256, 0, stream>>>(cparts, objinit, p, q, t, denom, c, best2, flag, 0, 0);

    for (int k = 0; k < KMAX; ++k) {
        const int kd = (k < KMAX - 1) ? k : 0;   // last iter: only obj needed
        conv_bro_kernel<<<CG, 64, 0, stream>>>(zb, WA, uxb, xv, gxb, updb, dgxb,
                                               Us, VTs, cparts, kd);
        if (k < KMAX - 1) {
            small_kernel<<<1, 256, 0, stream>>>(cparts, objinit, p, q, t,
                                                denom, c, best2, flag, k, 1);
            pass2_kernel<<<dim3(DDIM / 2048, NB), 256, 0, stream>>>(
                Us, VTs, updb, dgxb, gxb, xv, zb, bestzb, p, q, t, denom, c, flag, k);
        } else {
            small_kernel<<<1, 256, 0, stream>>>(cparts, objinit, p, q, t,
                                                denom, c, best2, flag, k, 2);
            bestcopy_kernel<<<I8WG, 256, 0, stream>>>(flag, zb, bestzb);
        }
    }

    // zn = relu(conv(best,A) + ux_fp32) -> NCHW out
    conv_final_kernel<<<CG, 64, 0, stream>>>(bestzb, WA, ux, out);
}

// Round 6
// 1833.766 us; speedup vs baseline: 1.0514x; 1.0514x over previous
//
#include <hip/hip_runtime.h>

// Problem constants (fixed by reference setup_inputs)
#define NB    16              // batch
#define CIN_  64              // input channels of x
#define COUT_ 128             // channels of z / output
#define PLANE_ 1024           // 32*32
#define DDIM  (COUT_*PLANE_)  // 131072
#define BDTOT ((size_t)NB*DDIM) // 2097152
#define KMAX  20              // Broyden threshold
#define SMAX  8               // split-K for dots
#define SEG   (DDIM / SMAX)   // 16384
#define GRP8  (SEG / 8)       // 2048 8-elem groups per segment

typedef short  bfrag __attribute__((ext_vector_type(8)));  // 8 bf16 (4 VGPRs)
typedef float  ffrag __attribute__((ext_vector_type(4)));  // 4 fp32 acc

// bf16 <-> fp32 helpers (RNE)
__device__ __forceinline__ float bf2f(unsigned short h) {
    return __uint_as_float(((unsigned int)h) << 16);
}
__device__ __forceinline__ unsigned short f2bf(float f) {
    unsigned int u = __float_as_uint(f);
    u = (u + 0x7FFFu + ((u >> 16) & 1u)) >> 16;
    return (unsigned short)u;
}
__device__ __forceinline__ void bf2x(unsigned int w, float& lo, float& hi) {
    lo = __uint_as_float(w << 16);
    hi = __uint_as_float(w & 0xffff0000u);
}
__device__ __forceinline__ unsigned int packbf(float lo, float hi) {
    return ((unsigned int)f2bf(hi) << 16) | (unsigned int)f2bf(lo);
}
__device__ __forceinline__ void ub4(ushort4 a, float* f) {
    f[0] = bf2f(a.x); f[1] = bf2f(a.y); f[2] = bf2f(a.z); f[3] = bf2f(a.w);
}
__device__ __forceinline__ ushort4 pk4(const float* f) {
    ushort4 r; r.x = f2bf(f[0]); r.y = f2bf(f[1]); r.z = f2bf(f[2]); r.w = f2bf(f[3]);
    return r;
}
__device__ __forceinline__ void ub8(uint4 a, float* f) {
    bf2x(a.x, f[0], f[1]); bf2x(a.y, f[2], f[3]);
    bf2x(a.z, f[4], f[5]); bf2x(a.w, f[6], f[7]);
}
__device__ __forceinline__ float wred(float v) {
    #pragma unroll
    for (int m = 32; m > 0; m >>= 1) v += __shfl_xor(v, m, 64);
    return v;
}

// ---------------------------------------------------------------------------
// Shared MFMA conv core: one wave = 32co x 32px tile, NHWC bf16 input.
// ---------------------------------------------------------------------------
template<int CIN>
__device__ __forceinline__ void conv_core(
    const unsigned short* __restrict__ zb, const unsigned short* __restrict__ Wt,
    int hrow, int co_base, int n, int col, int quad, ffrag accs[4])
{
    const bfrag bzero = {0,0,0,0,0,0,0,0};
    const int w0 = col, w1 = col + 16;
    const size_t zbase = (size_t)n * PLANE_ * CIN;
    #pragma unroll
    for (int tap = 0; tap < 9; ++tap) {
        const int dh = tap / 3 - 1, dw = tap % 3 - 1;
        const int sh = hrow + dh;
        const bool rowok = (unsigned)sh < 32u;
        const int sw0 = w0 + dw, sw1 = w1 + dw;
        const bool v0 = rowok && (unsigned)sw0 < 32u;
        const bool v1 = rowok && (unsigned)sw1 < 32u;
        const int sp0 = v0 ? (sh * 32 + sw0) : (hrow * 32 + w0);
        const int sp1 = v1 ? (sh * 32 + sw1) : (hrow * 32 + w1);
        const unsigned short* z0 = zb + zbase + (size_t)sp0 * CIN + quad * 8;
        const unsigned short* z1 = zb + zbase + (size_t)sp1 * CIN + quad * 8;
        const unsigned short* wr0 = Wt + ((size_t)tap * COUT_ + co_base + col) * CIN + quad * 8;
        const unsigned short* wr1 = wr0 + 16 * CIN;
        #pragma unroll
        for (int cb = 0; cb < CIN; cb += 32) {
            bfrag a0 = *(const bfrag*)(wr0 + cb);
            bfrag a1 = *(const bfrag*)(wr1 + cb);
            bfrag b0 = *(const bfrag*)(z0 + cb);
            bfrag b1 = *(const bfrag*)(z1 + cb);
            if (!v0) b0 = bzero;
            if (!v1) b1 = bzero;
            accs[0] = __builtin_amdgcn_mfma_f32_16x16x32_bf16(a0, b0, accs[0], 0, 0, 0);
            accs[1] = __builtin_amdgcn_mfma_f32_16x16x32_bf16(a0, b1, accs[1], 0, 0, 0);
            accs[2] = __builtin_amdgcn_mfma_f32_16x16x32_bf16(a1, b0, accs[2], 0, 0, 0);
            accs[3] = __builtin_amdgcn_mfma_f32_16x16x32_bf16(a1, b1, accs[3], 0, 0, 0);
        }
    }
}

// ---------------------------------------------------------------------------
// ux = conv(x,U) + b : writes fp32 ux (final recompute) + bf16 uxb (loop).
// ---------------------------------------------------------------------------
__global__ __launch_bounds__(64) void conv_ux_kernel(
    const unsigned short* __restrict__ xinb, const unsigned short* __restrict__ WU,
    const float* __restrict__ bias, float* __restrict__ ux,
    unsigned short* __restrict__ uxb)
{
    const int hrow = blockIdx.x, coT = blockIdx.y, n = blockIdx.z;
    const int lane = threadIdx.x, col = lane & 15, quad = lane >> 4;
    ffrag accs[4] = {{0.f,0.f,0.f,0.f},{0.f,0.f,0.f,0.f},{0.f,0.f,0.f,0.f},{0.f,0.f,0.f,0.f}};
    conv_core<CIN_>(xinb, WU, hrow, coT * 32, n, col, quad, accs);
    #pragma unroll
    for (int f = 0; f < 4; ++f) {
        const int mt = f >> 1, nt = f & 1;
        const int co = coT * 32 + mt * 16 + quad * 4;
        const int px = hrow * 32 + nt * 16 + col;
        const size_t o = ((size_t)n * PLANE_ + px) * COUT_ + co;
        float4 bv = *(const float4*)(bias + co);
        float r[4] = {accs[f][0] + bv.x, accs[f][1] + bv.y, accs[f][2] + bv.z, accs[f][3] + bv.w};
        *(float4*)(ux + o) = make_float4(r[0], r[1], r[2], r[3]);
        *(ushort4*)(uxb + o) = pk4(r);
    }
}

// ---------------------------------------------------------------------------
// Broyden conv: g = relu(conv(z,A)+ux) - x ; dgx = g - gx_old (gx in place)
// Fused STATE-ONLY scalars (no history!): dd=dx.dgx, dg1=dx.g, obj=g.g
// cparts[(row*NB+n)*128 + blk], rows 0..2, blk = hrow*4+coT.
// ---------------------------------------------------------------------------
__global__ __launch_bounds__(64) void conv_bro_kernel(
    const unsigned short* __restrict__ zb, const unsigned short* __restrict__ WA,
    const unsigned short* __restrict__ uxb, const float* __restrict__ xv,
    unsigned short* gxb,                       // rw (old -> new)
    const unsigned short* __restrict__ updb,   // dx
    unsigned short* __restrict__ dgxb,
    float* __restrict__ cparts)
{
    const int hrow = blockIdx.x, coT = blockIdx.y, n = blockIdx.z;
    const int lane = threadIdx.x, col = lane & 15, quad = lane >> 4;
    ffrag accs[4] = {{0.f,0.f,0.f,0.f},{0.f,0.f,0.f,0.f},{0.f,0.f,0.f,0.f},{0.f,0.f,0.f,0.f}};
    conv_core<COUT_>(zb, WA, hrow, coT * 32, n, col, quad, accs);

    const int blk = hrow * 4 + coT;
    float sdd = 0.f, sdg = 0.f, sob = 0.f;
    #pragma unroll
    for (int f = 0; f < 4; ++f) {
        const int mt = f >> 1, nt = f & 1;
        const int co = coT * 32 + mt * 16 + quad * 4;
        const int px = hrow * 32 + nt * 16 + col;
        const size_t o = ((size_t)n * PLANE_ + px) * COUT_ + co;
        float uxv[4], gov[4], udv[4];
        ub4(*(const ushort4*)(uxb + o), uxv);
        ub4(*(const ushort4*)(gxb + o), gov);
        ub4(*(const ushort4*)(updb + o), udv);
        float4 xc = *(const float4*)(xv + o);
        float g[4], dgv[4];
        #pragma unroll
        for (int r = 0; r < 4; ++r) {
            float tv = accs[f][r] + uxv[r];
            tv = tv > 0.f ? tv : 0.f;
            g[r] = tv - (&xc.x)[r];
            dgv[r] = g[r] - gov[r];
            sdd += udv[r] * dgv[r];
            sdg += udv[r] * g[r];
            sob += g[r] * g[r];
        }
        *(ushort4*)(gxb + o)  = pk4(g);
        *(ushort4*)(dgxb + o) = pk4(dgv);
    }
    sdd = wred(sdd); sdg = wred(sdg); sob = wred(sob);
    if (lane == 0) {
        cparts[((size_t)0 * NB + n) * 128 + blk] = sdd;
        cparts[((size_t)1 * NB + n) * 128 + blk] = sdg;
        cparts[((size_t)2 * NB + n) * 128 + blk] = sob;
    }
}

// ---------------------------------------------------------------------------
// Final recompute: out = relu(conv(best,A) + ux_fp32)  -> NCHW
// ---------------------------------------------------------------------------
__global__ __launch_bounds__(64) void conv_final_kernel(
    const unsigned short* __restrict__ bestzb, const unsigned short* __restrict__ WA,
    const float* __restrict__ ux, float* __restrict__ out)
{
    const int hrow = blockIdx.x, coT = blockIdx.y, n = blockIdx.z;
    const int lane = threadIdx.x, col = lane & 15, quad = lane >> 4;
    ffrag accs[4] = {{0.f,0.f,0.f,0.f},{0.f,0.f,0.f,0.f},{0.f,0.f,0.f,0.f},{0.f,0.f,0.f,0.f}};
    conv_core<COUT_>(bestzb, WA, hrow, coT * 32, n, col, quad, accs);
    #pragma unroll
    for (int f = 0; f < 4; ++f) {
        const int mt = f >> 1, nt = f & 1;
        const int co = coT * 32 + mt * 16 + quad * 4;
        const int px = hrow * 32 + nt * 16 + col;
        const size_t o = ((size_t)n * PLANE_ + px) * COUT_ + co;
        float4 uv = *(const float4*)(ux + o);
        #pragma unroll
        for (int r = 0; r < 4; ++r) {
            float t = accs[f][r] + (&uv.x)[r];
            out[((size_t)n * COUT_ + co + r) * PLANE_ + px] = t > 0.f ? t : 0.f;
        }
    }
}

// ---------------------------------------------------------------------------
// One-time prep
// ---------------------------------------------------------------------------
#define NWA (9 * 128 * 128)
#define NWU (9 * 128 * 64)
__global__ __launch_bounds__(256) void prep_w_kernel(
    const float* __restrict__ A, const float* __restrict__ U,
    unsigned short* __restrict__ WA, unsigned short* __restrict__ WU)
{
    int idx = blockIdx.x * 256 + threadIdx.x;
    if (idx < NWA) {
        int tap = idx / (128 * 128), r = idx % (128 * 128);
        int co = r >> 7, ci = r & 127;
        WA[idx] = f2bf(A[(co * 128 + ci) * 9 + tap]);
    } else if (idx < NWA + NWU) {
        int j = idx - NWA;
        int tap = j / (128 * 64), r = j % (128 * 64);
        int co = r >> 6, ci = r & 63;
        WU[j] = f2bf(U[(co * 64 + ci) * 9 + tap]);
    }
}

__global__ __launch_bounds__(256) void prep_xin_kernel(
    const float* __restrict__ x, unsigned short* __restrict__ xb)
{
    int idx = blockIdx.x * 256 + threadIdx.x;   // over 16*1024*64
    int n = idx >> 16, r = idx & 65535;
    int px = r >> 6, ci = r & 63;
    xb[idx] = f2bf(x[(n * 64 + ci) * 1024 + px]);
}

__global__ __launch_bounds__(256) void fill0_kernel(float* __restrict__ a)
{
    size_t i = ((size_t)blockIdx.x * 256 + threadIdx.x) * 4;
    *(float4*)(a + i) = make_float4(0.f, 0.f, 0.f, 0.f);
}

// ---------------------------------------------------------------------------
// Init: gx0 = upd0 = relu(ux) (bf16-rounded), x1 = same (fp32), zb mirror,
// per-block obj partial -> objinit[1024].
// ---------------------------------------------------------------------------
__global__ __launch_bounds__(256) void ew_init_kernel(
    const float* __restrict__ ux, unsigned short* __restrict__ gxb,
    unsigned short* __restrict__ updb, float* __restrict__ xv,
    unsigned short* __restrict__ zb, float* __restrict__ objinit)
{
    const int tid = threadIdx.x;
    size_t i = ((size_t)blockIdx.x * 256 + tid) * 8;
    float rr[8];
    float ob = 0.f;
    #pragma unroll
    for (int h = 0; h < 2; ++h) {
        float4 u = *(const float4*)(ux + i + h * 4);
        #pragma unroll
        for (int r = 0; r < 4; ++r) {
            float v = (&u.x)[r];
            v = v > 0.f ? v : 0.f;
            v = bf2f(f2bf(v));           // round once, use consistently
            rr[h*4+r] = v;
            ob += v * v;
        }
    }
    uint4 m = {packbf(rr[0],rr[1]), packbf(rr[2],rr[3]), packbf(rr[4],rr[5]), packbf(rr[6],rr[7])};
    *(uint4*)(gxb  + i) = m;
    *(uint4*)(updb + i) = m;
    *(uint4*)(zb   + i) = m;
    #pragma unroll
    for (int h = 0; h < 2; ++h)
        *(float4*)(xv + i + h * 4) = make_float4(rr[h*4+0], rr[h*4+1], rr[h*4+2], rr[h*4+3]);

    __shared__ float so[256];
    so[tid] = ob;
    __syncthreads();
    for (int s = 128; s > 0; s >>= 1) {
        if (tid < s) so[tid] += so[tid + s];
        __syncthreads();
    }
    if (tid == 0) objinit[blockIdx.x] = so[0];
}

// ---------------------------------------------------------------------------
// Split-K dots over VTs ONLY: q_i = v_i.dgx, t_i = v_i.g  (one VTs read).
// grid (NB, k, SMAX), 256 thr. tparts[((i*NB+b)*SMAX+s)*2 + {0,1}]
// ---------------------------------------------------------------------------
__global__ __launch_bounds__(256) void dots_kernel(
    const unsigned short* __restrict__ VTs,
    const unsigned short* __restrict__ dgxb, const unsigned short* __restrict__ gxb,
    float* __restrict__ tparts)
{
    const int b = blockIdx.x, i = blockIdx.y, s = blockIdx.z;
    const int tid = threadIdx.x;
    const size_t segbase = (size_t)b * DDIM + (size_t)s * SEG;
    const uint4* v8 = (const uint4*)(VTs + (size_t)i * BDTOT + segbase);
    const uint4* d8 = (const uint4*)(dgxb + segbase);
    const uint4* g8 = (const uint4*)(gxb + segbase);
    float s0 = 0.f, s1 = 0.f;
    for (int g = tid; g < GRP8; g += 256) {
        float vv[8], dv[8], gv[8];
        ub8(v8[g], vv); ub8(d8[g], dv); ub8(g8[g], gv);
        #pragma unroll
        for (int j = 0; j < 8; ++j) {
            s0 = fmaf(vv[j], dv[j], s0);
            s1 = fmaf(vv[j], gv[j], s1);
        }
    }
    __shared__ float r0[256], r1[256];
    r0[tid] = s0; r1[tid] = s1;
    __syncthreads();
    for (int st = 128; st > 0; st >>= 1) {
        if (tid < st) { r0[tid] += r0[tid + st]; r1[tid] += r1[tid + st]; }
        __syncthreads();
    }
    if (tid == 0) {
        size_t o = (((size_t)i * NB + b) * SMAX + s) * 2;
        tparts[o] = r0[0];      // q partial
        tparts[o + 1] = r1[0];  // t partial
    }
}

// ---------------------------------------------------------------------------
// Fold partials; scalar math; best tracking.
// phase 0: best2 = sum objinit. phase 1: full. phase 2: obj only.
// p from pparts (written by pass2 at iteration k-1), q/t from tparts,
// dd/dg1/obj from cparts.
// ---------------------------------------------------------------------------
__global__ __launch_bounds__(256) void small_kernel(
    const float* __restrict__ cparts, const float* __restrict__ tparts,
    const float* __restrict__ pparts, const float* __restrict__ objinit,
    float* __restrict__ p, float* __restrict__ q, float* __restrict__ t,
    float* __restrict__ denom, float* __restrict__ c,
    float* __restrict__ best2, float* __restrict__ flag,
    int k, int phase)
{
    const int tid = threadIdx.x;
    if (phase == 1 && k > 0) {
        for (int idx = tid; idx < NB * k; idx += 256) {
            int b = idx / k, i = idx - b * k;
            float qv = 0.f, tv = 0.f;
            #pragma unroll
            for (int s = 0; s < SMAX; ++s) {
                size_t o = (((size_t)i * NB + b) * SMAX + s) * 2;
                qv += tparts[o];
                tv += tparts[o + 1];
            }
            float pv = 0.f;
            const float* P = pparts + ((size_t)i * NB + b) * 256;
            for (int j = 0; j < 256; ++j) pv += P[j];
            q[b * KMAX + i] = qv; t[b * KMAX + i] = tv; p[b * KMAX + i] = pv;
        }
    }
    __syncthreads();
    if (phase == 1 && tid < NB) {
        int b = tid;
        const float* DD = cparts + ((size_t)0 * NB + b) * 128;
        const float* DG = cparts + ((size_t)1 * NB + b) * 128;
        float ddv = 0.f, dgv = 0.f;
        for (int j = 0; j < 128; ++j) { ddv += DD[j]; dgv += DG[j]; }
        float pq = 0.f, pt = 0.f;
        for (int i = 0; i < k; ++i) {
            pq += p[b * KMAX + i] * q[b * KMAX + i];
            pt += p[b * KMAX + i] * t[b * KMAX + i];
        }
        float den = -ddv + pq;
        if (fabsf(den) < 1e-9f) den = 1e-9f;
        denom[b] = den;
        c[b] = (-dgv + pt) / den;
    }
    // objective (all phases)
    float o = 0.f;
    if (phase == 0) {
        for (int j = tid; j < 1024; j += 256) o += objinit[j];
    } else {
        const float* OB = cparts + (size_t)2 * NB * 128;
        for (int j = tid; j < NB * 128; j += 256) o += OB[j];
    }
    __shared__ float so[256];
    so[tid] = o;
    __syncthreads();
    for (int s = 128; s > 0; s >>= 1) {
        if (tid < s) so[tid] += so[tid + s];
        __syncthreads();
    }
    if (tid == 0) {
        float ot = so[0];
        if (phase == 0) { *best2 = ot; *flag = 0.f; }
        else {
            float bo = *best2;
            *flag = (ot < bo) ? 1.f : 0.f;
            if (ot < bo) *best2 = ot;
        }
    }
}

// ---------------------------------------------------------------------------
// Fused big pass: history read once (HBM); writes new rows; advances x;
// mirrors; then a SECOND loop over Us (LLC-hot) computes next-iteration
// p_i = u_i . upd_new partials (per-wave) -> pparts[(i*NB+b)*256 + bx*4+wv].
// grid = (DDIM/2048 = 64, NB), 8 elems/thread, 256 thr (4 waves).
// ---------------------------------------------------------------------------
__global__ __launch_bounds__(256) void pass2_kernel(
    unsigned short* __restrict__ Us, unsigned short* __restrict__ VTs,
    unsigned short* updb,                 // rw: dx in, new update out
    const unsigned short* __restrict__ dgxb, const unsigned short* __restrict__ gxb,
    float* xv, unsigned short* __restrict__ zb, unsigned short* __restrict__ bestzb,
    const float* __restrict__ p, const float* __restrict__ q, const float* __restrict__ t,
    const float* __restrict__ denom, const float* __restrict__ c,
    const float* __restrict__ flag, float* __restrict__ pparts, int k)
{
    const int b = blockIdx.y;
    const int bx = blockIdx.x;
    const int tid = threadIdx.x;
    __shared__ float sp[KMAX], sq[KMAX], st[KMAX];
    __shared__ float sden, sc, sflag;
    if (tid < k) {
        sp[tid] = p[b * KMAX + tid];
        sq[tid] = q[b * KMAX + tid];
        st[tid] = t[b * KMAX + tid];
    }
    if (tid == 0) { sden = denom[b]; sc = c[b]; sflag = flag[0]; }
    __syncthreads();

    const size_t base = (size_t)b * DDIM + ((size_t)bx * 256 + tid) * 8;
    float xd[8], dg[8], gv[8];
    ub8(*(const uint4*)(updb + base), xd);
    ub8(*(const uint4*)(dgxb + base), dg);
    ub8(*(const uint4*)(gxb  + base), gv);

    float S1[8], S2[8], SV[8];
    #pragma unroll
    for (int j = 0; j < 8; ++j) { S1[j] = 0.f; S2[j] = 0.f; SV[j] = 0.f; }

    for (int i = 0; i < k; ++i) {
        float uvals[8], vvals[8];
        ub8(*(const uint4*)(Us  + (size_t)i * BDTOT + base), uvals);
        ub8(*(const uint4*)(VTs + (size_t)i * BDTOT + base), vvals);
        float qi = sq[i], ti = st[i], pi = sp[i];
        #pragma unroll
        for (int j = 0; j < 8; ++j) {
            S1[j] = fmaf(qi, uvals[j], S1[j]);
            S2[j] = fmaf(ti, uvals[j], S2[j]);
            SV[j] = fmaf(pi, vvals[j], SV[j]);
        }
    }

    float vk[8], uk[8], up[8];
    #pragma unroll
    for (int j = 0; j < 8; ++j) {
        vk[j] = -xd[j] + SV[j];
        uk[j] = (xd[j] + dg[j] - S1[j]) / sden;
        up[j] = gv[j] - sc * (xd[j] + dg[j]) - S2[j] + sc * S1[j];
    }
    uint4 vks = {packbf(vk[0],vk[1]), packbf(vk[2],vk[3]), packbf(vk[4],vk[5]), packbf(vk[6],vk[7])};
    uint4 uks = {packbf(uk[0],uk[1]), packbf(uk[2],uk[3]), packbf(uk[4],uk[5]), packbf(uk[6],uk[7])};
    *(uint4*)(VTs + (size_t)k * BDTOT + base) = vks;
    *(uint4*)(Us  + (size_t)k * BDTOT + base) = uks;

    uint4 upw = {packbf(up[0],up[1]), packbf(up[2],up[3]), packbf(up[4],up[5]), packbf(up[6],up[7])};
    *(uint4*)(updb + base) = upw;
    float upr[8];
    ub8(upw, upr);

    float xc[8];
    #pragma unroll
    for (int h = 0; h < 2; ++h) {
        float4 a = *(const float4*)(xv + base + h * 4);
        xc[h*4+0]=a.x; xc[h*4+1]=a.y; xc[h*4+2]=a.z; xc[h*4+3]=a.w;
    }
    if (sflag != 0.f) {
        uint4 bz = {packbf(xc[0],xc[1]), packbf(xc[2],xc[3]),
                    packbf(xc[4],xc[5]), packbf(xc[6],xc[7])};
        *(uint4*)(bestzb + base) = bz;
    }
    float xn[8];
    #pragma unroll
    for (int j = 0; j < 8; ++j) xn[j] = xc[j] + upr[j];
    #pragma unroll
    for (int h = 0; h < 2; ++h)
        *(float4*)(xv + base + h * 4) = make_float4(xn[h*4+0], xn[h*4+1], xn[h*4+2], xn[h*4+3]);
    uint4 zn = {packbf(xn[0],xn[1]), packbf(xn[2],xn[3]), packbf(xn[4],xn[5]), packbf(xn[6],xn[7])};
    *(uint4*)(zb + base) = zn;

    // ---- second loop: next-iteration p_i = u_i . upd (bf16 values) ----
    const int wv = tid >> 6;   // wave 0..3
    for (int i = 0; i < k; ++i) {
        float uvals[8];
        ub8(*(const uint4*)(Us + (size_t)i * BDTOT + base), uvals);  // LLC-hot
        float pp = 0.f;
        #pragma unroll
        for (int j = 0; j < 8; ++j) pp = fmaf(uvals[j], upr[j], pp);
        pp = wred(pp);
        if ((tid & 63) == 0)
            pparts[((size_t)i * NB + b) * 256 + bx * 4 + wv] = pp;
    }
    {   // new row k from registers (bf16-rounded values)
        float ukr[8];
        ub8(uks, ukr);
        float pp = 0.f;
        #pragma unroll
        for (int j = 0; j < 8; ++j) pp = fmaf(ukr[j], upr[j], pp);
        pp = wred(pp);
        if ((tid & 63) == 0)
            pparts[((size_t)k * NB + b) * 256 + bx * 4 + wv] = pp;
    }
}

// best mirror = zb when new best (last iteration only)
__global__ __launch_bounds__(256) void bestcopy_kernel(
    const float* __restrict__ flag, const unsigned short* __restrict__ zb,
    unsigned short* __restrict__ bestzb)
{
    if (flag[0] == 0.f) return;
    size_t i = ((size_t)blockIdx.x * 256 + threadIdx.x) * 8;
    *(uint4*)(bestzb + i) = *(const uint4*)(zb + i);
}

// ---------------------------------------------------------------------------
extern "C" void kernel_launch(void* const* d_in, const int* in_sizes, int n_in,
                              void* d_out, int out_size, void* d_ws, size_t ws_size,
                              hipStream_t stream)
{
    (void)in_sizes; (void)n_in; (void)out_size; (void)ws_size;
    const float* x  = (const float*)d_in[0];   // [16,64,32,32]
    const float* A  = (const float*)d_in[1];   // [128,128,3,3]
    const float* U  = (const float*)d_in[2];   // [128,64,3,3]
    const float* bb = (const float*)d_in[3];   // [128]
    float* out = (float*)d_out;

    char* w = (char*)d_ws;
    size_t off = 0;
    auto alloc = [&](size_t bytes) -> void* {
        void* pp = (void*)(w + off);
        off += (bytes + 255) & ~(size_t)255;
        return pp;
    };
    const size_t BDB  = BDTOT * sizeof(float);  // 8 MB
    const size_t BDH  = BDTOT * 2;              // 4 MB (bf16)
    float* ux    = (float*)alloc(BDB);          // fp32 (final recompute)
    float* xv    = (float*)alloc(BDB);          // fp32 iterate accumulator
    unsigned short* uxb    = (unsigned short*)alloc(BDH);
    unsigned short* gxb    = (unsigned short*)alloc(BDH);
    unsigned short* updb   = (unsigned short*)alloc(BDH);
    unsigned short* dgxb   = (unsigned short*)alloc(BDH);
    unsigned short* zb     = (unsigned short*)alloc(BDH);
    unsigned short* bestzb = (unsigned short*)alloc(BDH);
    unsigned short* xinb   = (unsigned short*)alloc((size_t)NB * PLANE_ * CIN_ * 2);
    unsigned short* WA     = (unsigned short*)alloc((size_t)NWA * 2);
    unsigned short* WU     = (unsigned short*)alloc((size_t)NWU * 2);
    unsigned short* Us  = (unsigned short*)alloc((size_t)KMAX * BDTOT * 2); // 84 MB
    unsigned short* VTs = (unsigned short*)alloc((size_t)KMAX * BDTOT * 2); // 84 MB
    float* cparts = (float*)alloc((size_t)3 * NB * 128 * sizeof(float));
    float* tparts = (float*)alloc((size_t)KMAX * NB * SMAX * 2 * sizeof(float));
    float* pparts = (float*)alloc((size_t)KMAX * NB * 256 * sizeof(float));
    float* objinit= (float*)alloc(1024 * sizeof(float));
    float* p     = (float*)alloc(NB * KMAX * sizeof(float));
    float* q     = (float*)alloc(NB * KMAX * sizeof(float));
    float* t     = (float*)alloc(NB * KMAX * sizeof(float));
    float* denom = (float*)alloc(NB * sizeof(float));
    float* c     = (float*)alloc(NB * sizeof(float));
    float* best2 = (float*)alloc(sizeof(float));
    float* flag  = (float*)alloc(sizeof(float));

    const dim3 CG(32, 4, NB);                   // conv grid, 64-thr blocks
    const int I8WG = (int)(BDTOT / (256 * 8));  // 1024 blocks, 8 elems/thread

    // -------- one-time prep --------
    prep_w_kernel<<<(NWA + NWU + 255) / 256, 256, 0, stream>>>(A, U, WA, WU);
    prep_xin_kernel<<<(NB * PLANE_ * CIN_) / 256, 256, 0, stream>>>(x, xinb);
    fill0_kernel<<<(int)(BDH / (256 * 16)), 256, 0, stream>>>((float*)bestzb); // best = x0 = 0

    // ux = conv(x,U)+b (fp32 + bf16)
    conv_ux_kernel<<<CG, 64, 0, stream>>>(xinb, WU, bb, ux, uxb);
    // gx0 = upd0 = relu(ux); x1 = same; zb mirror; obj partials
    ew_init_kernel<<<I8WG, 256, 0, stream>>>(ux, gxb, updb, xv, zb, objinit);
    small_kernel<<<1, 256, 0, stream>>>(cparts, tparts, pparts, objinit,
                                        p, q, t, denom, c, best2, flag, 0, 0);

    for (int k = 0; k < KMAX; ++k) {
        conv_bro_kernel<<<CG, 64, 0, stream>>>(zb, WA, uxb, xv, gxb, updb, dgxb, cparts);
        if (k < KMAX - 1) {
            if (k > 0)
                dots_kernel<<<dim3(NB, k, SMAX), 256, 0, stream>>>(VTs, dgxb, gxb, tparts);
            small_kernel<<<1, 256, 0, stream>>>(cparts, tparts, pparts, objinit,
                                                p, q, t, denom, c, best2, flag, k, 1);
            pass2_kernel<<<dim3(DDIM / 2048, NB), 256, 0, stream>>>(
                Us, VTs, updb, dgxb, gxb, xv, zb, bestzb,
                p, q, t, denom, c, flag, pparts, k);
        } else {
            small_kernel<<<1, 256, 0, stream>>>(cparts, tparts, pparts, objinit,
                                                p, q, t, denom, c, best2, flag, k, 2);
            bestcopy_kernel<<<I8WG, 256, 0, stream>>>(flag, zb, bestzb);
        }
    }

    // zn = relu(conv(best,A) + ux_fp32) -> NCHW out
    conv_final_kernel<<<CG, 64, 0, stream>>>(bestzb, WA, ux, out);
}